// Round 4
// baseline (191.129 us; speedup 1.0000x reference)
//
#include <hip/hip_runtime.h>

#define BB 4
#define HH 1024
#define WW 1024
#define K2 9
#define PAD 1

#define TW 128            // tile width  (4 px per thread along w)
#define TH 8              // tile height
#define R  12             // halo radius (~6 sigma of offset)
#define RW (TW + 2*R)     // 152
#define RH (TH + 2*R)     // 32
#define RSZ (RW * RH)     // 4864 = 19 * 256

typedef float f32x4 __attribute__((ext_vector_type(4)));

__global__ __launch_bounds__(256) void dcn_kernel(
    const float* __restrict__ init_dem,   // [B,1,H,W]
    const float* __restrict__ weight,     // [B,K2,H,W]
    const float* __restrict__ offset,     // [B,2*K2,H,W]
    const float* __restrict__ wk,         // [K2]
    const float* __restrict__ bias,       // [1]
    float* __restrict__ out)              // [B,1,H,W]
{
    __shared__ float region[RSZ];

    const int HW = HH * WW;

    // batch pinned to an XCD pair (blockIdx % 8 -> XCD heuristic)
    int i    = blockIdx.x;
    int b    = (i & 7) >> 1;
    int widx = ((i >> 3) << 1) | (i & 1);   // 0..1023, bijective
    int tile_w = widx & 7;                  // WW/TW = 8
    int tile_h = widx >> 3;                 // HH/TH = 128
    int w0 = tile_w * TW;
    int h0 = tile_h * TH;

    const float* img = init_dem + (size_t)b * HW;

    // ---- stage image region (halo included, zeros outside image) ----
    int tid = threadIdx.x;
#pragma unroll
    for (int it = 0; it < RSZ / 256; ++it) {
        int e = tid + it * 256;
        int r = e / RW;
        int c = e - r * RW;
        int gy = h0 - R + r;
        int gx = w0 - R + c;
        float v = 0.f;
        if ((unsigned)gy < (unsigned)HH && (unsigned)gx < (unsigned)WW)
            v = img[gy * WW + gx];
        region[e] = v;
    }
    __syncthreads();

    const int tx4 = (tid & 31) << 2;        // 0,4,...,124
    const int ty  = tid >> 5;               // 0..7
    const int h   = h0 + ty;
    const int w   = w0 + tx4;
    const int rem = h * WW + w;

    const float* wq = weight + (size_t)b * K2 * HW + rem;
    const float* oq = offset + (size_t)b * 2 * K2 * HW + rem;

    float accA[4] = {0.f, 0.f, 0.f, 0.f};   // sum samp*wt*wk
    float accB[4] = {0.f, 0.f, 0.f, 0.f};   // sum samp*wk
    float msum[4] = {0.f, 0.f, 0.f, 0.f};   // sum wt

#pragma unroll
    for (int k = 0; k < K2; ++k) {
        f32x4 wtv = __builtin_nontemporal_load((const f32x4*)(wq + (size_t)k * HW));
        f32x4 dyv = __builtin_nontemporal_load((const f32x4*)(oq + (size_t)(2 * k) * HW));
        f32x4 dxv = __builtin_nontemporal_load((const f32x4*)(oq + (size_t)(2 * k + 1) * HW));
        const float wkk = wk[k];
        const int ky = k / 3, kx = k % 3;

#pragma unroll
        for (int p = 0; p < 4; ++p) {
            float dy = dyv[p], dx = dxv[p], wt = wtv[p];
            msum[p] += wt;

            float ys = (float)(h - PAD + ky) + dy;
            float xs = (float)(w + p - PAD + kx) + dx;

            float y0f = floorf(ys);
            float x0f = floorf(xs);
            float wy1 = ys - y0f;
            float wx1 = xs - x0f;
            float wy0 = 1.f - wy1;
            float wx0 = 1.f - wx1;

            int y0g = (int)y0f;
            int x0g = (int)x0f;
            int y0l = y0g - (h0 - R);
            int x0l = x0g - (w0 - R);

            float v00, v01, v10, v11;
            bool fast = (y0l >= 0) & (y0l < RH - 1) & (x0l >= 0) & (x0l < RW - 1);
            if (fast) {
                int base = y0l * RW + x0l;
                v00 = region[base];
                v01 = region[base + 1];
                v10 = region[base + RW];
                v11 = region[base + RW + 1];
            } else {
                int y1g = y0g + 1;
                int x1g = x0g + 1;
                bool y0v = (y0g >= 0) & (y0g < HH);
                bool y1v = (y1g >= 0) & (y1g < HH);
                bool x0v = (x0g >= 0) & (x0g < WW);
                bool x1v = (x1g >= 0) & (x1g < WW);
                int yc0 = min(max(y0g, 0), HH - 1);
                int yc1 = min(max(y1g, 0), HH - 1);
                int xc0 = min(max(x0g, 0), WW - 1);
                int xc1 = min(max(x1g, 0), WW - 1);
                v00 = (y0v & x0v) ? img[(size_t)yc0 * WW + xc0] : 0.f;
                v01 = (y0v & x1v) ? img[(size_t)yc0 * WW + xc1] : 0.f;
                v10 = (y1v & x0v) ? img[(size_t)yc1 * WW + xc0] : 0.f;
                v11 = (y1v & x1v) ? img[(size_t)yc1 * WW + xc1] : 0.f;
            }

            float samp = wy0 * (wx0 * v00 + wx1 * v01)
                       + wy1 * (wx0 * v10 + wx1 * v11);
            float sw = samp * wkk;
            accA[p] += sw * wt;
            accB[p] += sw;
        }
    }

    const float bval = bias[0];
    f32x4 res;
#pragma unroll
    for (int p = 0; p < 4; ++p) {
        float mean  = msum[p] * (1.0f / K2);
        float resid = region[(ty + R) * RW + (tx4 + R + p)];
        res[p] = accA[p] - mean * accB[p] + bval + resid;
    }
    __builtin_nontemporal_store(res, (f32x4*)(out + (size_t)b * HW + rem));
}

extern "C" void kernel_launch(void* const* d_in, const int* in_sizes, int n_in,
                              void* d_out, int out_size, void* d_ws, size_t ws_size,
                              hipStream_t stream) {
    const float* init_dem = (const float*)d_in[0];
    const float* weight   = (const float*)d_in[1];
    const float* offset   = (const float*)d_in[2];
    const float* wk       = (const float*)d_in[3];
    const float* bias     = (const float*)d_in[4];
    float* out            = (float*)d_out;

    const int nblocks = BB * (WW / TW) * (HH / TH);   // 4*8*128 = 4096
    dcn_kernel<<<dim3(nblocks), dim3(256), 0, stream>>>(init_dem, weight, offset, wk, bias, out);
}